// Round 4
// baseline (246.546 us; speedup 1.0000x reference)
//
#include <hip/hip_runtime.h>

// EMA scan: out[:,0,:] = x[:,0,:]; out[:,t,:] = 0.1*x[:,t,:] + 0.9*out[:,t-1,:]
// x: (16, 4096, 512) fp32.
//
// Strategy: chunk the T axis. The recurrence forgets at 0.9^W, so each chunk
// reconstructs its carry with a W>=64 warm-up from zero (error <= 0.9^64*|y|
// ~ 1.6e-3; measured absmax 0.0039, threshold 7.6e-2). No inter-block comms.
//
// R4: channel-decamping. Evidence so far: BW stuck at 2.5-2.8 TB/s regardless
// of wave count (R0 2w/CU vs R2 8w/CU: +13%) or per-wave pipeline depth
// (R3 = R0) -> the DRAM service rate for this pattern is the cap, not
// latency/occupancy. Theory: all 512 waves advance t in lockstep, and the
// parallel strides (chunk=512KB, b=8MB) alias to 0 mod the channel-interleave
// period -> at any instant every wave hits the same channel subset; channels
// are swept serially (~40% utilization = 2.5/6.3). Fix: stagger each chunk's
// warm-up length by ((5c+3b)&15) extra steps. The phase offset persists for
// the whole main loop -> concurrent waves spread over 16 distinct 2KB phases
// (32KB span) across channels. Accuracy strictly improves (W>=64).

constexpr int B = 16;
constexpr int T = 4096;
constexpr int D = 512;
constexpr int DV = D / 4;      // 128 float4 columns per (b, t) row
constexpr int L = 256;         // chunk length along T
constexpr int C = T / L;       // 16 chunks
constexpr int W = 64;          // base warm-up steps (0.9^64 ~ 1.2e-3)
constexpr int UNR = 8;         // loads in flight per wave

__global__ __launch_bounds__(64)
void ema_chunked_kernel(const float4* __restrict__ X, float4* __restrict__ O) {
    const int g     = blockIdx.x * 64 + threadIdx.x;
    const int dvec  = g & (DV - 1);          // consecutive within wave -> coalesced
    const int chunk = (g >> 7) & (C - 1);    // DV = 128 = 1<<7
    const int b     = g >> 11;               // DV*C = 2048 = 1<<11

    const float a  = 0.1f;
    const float bb = 0.9f;

    const int base = b * (T * DV) + dvec;    // max ~8.4M float4, fits int
    const int t0   = chunk * L;

    float4 y;
    if (chunk == 0) {
        // y_init = x0: main-loop step at t=0 gives 0.1*x0 + 0.9*x0 = x0 exactly.
        y = X[base];
    } else {
        // Phase stagger: 0..15 extra steps, unique per (chunk,b) mod 16.
        const int stag = (chunk * 5 + b * 3) & 15;
        y = make_float4(0.f, 0.f, 0.f, 0.f);

        // Oldest `stag` steps first (time order matters), simple serial loop.
        const float4* sp = X + base + (t0 - W - stag) * DV;
        for (int i = 0; i < stag; ++i) {
            float4 v = sp[i * DV];
            y.x = fmaf(bb, y.x, a * v.x);
            y.y = fmaf(bb, y.y, a * v.y);
            y.z = fmaf(bb, y.z, a * v.z);
            y.w = fmaf(bb, y.w, a * v.w);
        }

        // Then the fixed W=64 batched warm-up over [t0-W, t0).
        const float4* xp = X + base + (t0 - W) * DV;
        for (int tt = 0; tt < W; tt += UNR) {
            float4 v[UNR];
            #pragma unroll
            for (int j = 0; j < UNR; ++j) v[j] = xp[(tt + j) * DV];
            #pragma unroll
            for (int j = 0; j < UNR; ++j) {
                y.x = fmaf(bb, y.x, a * v[j].x);
                y.y = fmaf(bb, y.y, a * v[j].y);
                y.z = fmaf(bb, y.z, a * v[j].z);
                y.w = fmaf(bb, y.w, a * v[j].w);
            }
        }
    }

    const float4* xp = X + base + t0 * DV;
    float4*       op = O + base + t0 * DV;
    for (int tt = 0; tt < L; tt += UNR) {
        float4 v[UNR];
        #pragma unroll
        for (int j = 0; j < UNR; ++j) v[j] = xp[(tt + j) * DV];
        #pragma unroll
        for (int j = 0; j < UNR; ++j) {
            y.x = fmaf(bb, y.x, a * v[j].x);
            y.y = fmaf(bb, y.y, a * v[j].y);
            y.z = fmaf(bb, y.z, a * v[j].z);
            y.w = fmaf(bb, y.w, a * v[j].w);
            op[(tt + j) * DV] = y;
        }
    }
}

extern "C" void kernel_launch(void* const* d_in, const int* in_sizes, int n_in,
                              void* d_out, int out_size, void* d_ws, size_t ws_size,
                              hipStream_t stream) {
    const float4* X = (const float4*)d_in[0];
    float4*       O = (float4*)d_out;

    const int total_threads = B * C * DV;    // 32768
    const int block = 64;
    const int grid  = total_threads / block; // 512 blocks -> 2 waves/CU
    ema_chunked_kernel<<<grid, block, 0, stream>>>(X, O);
}

// Round 5
// 242.032 us; speedup vs baseline: 1.0187x; 1.0187x over previous
//
#include <hip/hip_runtime.h>

// EMA scan: out[:,0,:] = x[:,0,:]; out[:,t,:] = 0.1*x[:,t,:] + 0.9*out[:,t-1,:]
// x: (16, 4096, 512) fp32.
//
// Chunked along T: each chunk reconstructs its carry with a W=64 warm-up from
// zero (error <= 0.9^64*|y| ~ 1.6e-3; measured absmax 0.0039, thr 7.6e-2).
//
// R5: LDS-ring software pipeline with counted vmcnt.
// Evidence: BW stuck at 2.5-2.8 TB/s across wave counts (R0/R2) and a
// register-pipeline attempt the compiler collapsed (R3: VGPR=64 proves the
// A/B buffers never materialized). Theory: per-batch vmcnt DRAIN - loads for
// batch k+1 only issue after batch k's compute, so each wave pays a full
// ~2000cy loaded round-trip per 8 steps (8KB/wave in flight, duty-limited).
// Fix (GEMM T3/T4 pattern): global_load_lds into a 4-slot LDS ring, issue 3
// batches ahead, consume with counted s_waitcnt vmcnt(N) - never drain to 0.
// In-flight = 24KB/wave sustained, independent of VGPR allocator.
// vmcnt accounting (in-order retire, 8 loads + 8 stores per iter):
//   steady wait = 3*8 loads + 3*8 stores = vmcnt(48); prologue 24/32/40.
// Geometry identical to R0 (L=256, W=64, block=64, min traffic) - one var.

constexpr int B = 16;
constexpr int T = 4096;
constexpr int D = 512;
constexpr int DV = D / 4;      // 128 float4 columns per (b, t) row
constexpr int L = 256;         // chunk length along T
constexpr int C = T / L;       // 16 chunks
constexpr int W = 64;          // warm-up steps (0.9^64 ~ 1.2e-3)
constexpr int BATCH = 8;       // t-steps per pipeline stage (8 x 1KB = 8KB)
constexpr int SLOTS = 4;       // ring depth; 3 stages in flight

#define WAITVM(N) do { asm volatile("s_waitcnt vmcnt(" #N ")" ::: "memory"); \
                       __builtin_amdgcn_sched_barrier(0); } while (0)

typedef const __attribute__((address_space(1))) void* gaddr_t;
typedef __attribute__((address_space(3))) void* laddr_t;

__global__ __launch_bounds__(64)
void ema_lds_pipe(const float4* __restrict__ X, float4* __restrict__ O) {
    // ring[slot][j][lane]: lane stride 16B matches global_load_lds's fixed
    // dest layout (wave-uniform base + lane*16). 32 KiB total.
    __shared__ float4 ring[SLOTS][BATCH][64];

    const int lane  = threadIdx.x;
    const int g     = blockIdx.x * 64 + lane;
    const int dvec  = g & (DV - 1);          // consecutive in wave -> coalesced
    const int chunk = (g >> 7) & (C - 1);    // DV = 128 = 1<<7
    const int b     = g >> 11;               // DV*C = 2048 = 1<<11

    const float a  = 0.1f;
    const float bb = 0.9f;

    const int base   = b * (T * DV) + dvec;
    const int t0     = chunk * L;
    const int tstart = (chunk == 0) ? 0 : (t0 - W);
    const int nb     = (chunk == 0) ? (L / BATCH) : ((W + L) / BATCH); // 32 | 40

    const float4* xs = X + base + tstart * DV;  // per-lane global base
    float4*       os = O + base + tstart * DV;

    auto issue = [&](int ib) {
        const int ibc  = (ib < nb) ? ib : (nb - 1);  // tail: dummy re-issue
        const int slot = ib & (SLOTS - 1);
        const float4* gp = xs + ibc * (BATCH * DV);
        #pragma unroll
        for (int j = 0; j < BATCH; ++j)
            __builtin_amdgcn_global_load_lds((gaddr_t)(gp + j * DV),
                                             (laddr_t)&ring[slot][j][0],
                                             16, 0, 0);
    };

    float4 y = make_float4(0.f, 0.f, 0.f, 0.f);

    auto consume = [&](int i, bool st) {
        const int slot = i & (SLOTS - 1);
        float4 v[BATCH];
        #pragma unroll
        for (int j = 0; j < BATCH; ++j) v[j] = ring[slot][j][lane];
        #pragma unroll
        for (int j = 0; j < BATCH; ++j) {
            y.x = fmaf(bb, y.x, a * v[j].x);
            y.y = fmaf(bb, y.y, a * v[j].y);
            y.z = fmaf(bb, y.z, a * v[j].z);
            y.w = fmaf(bb, y.w, a * v[j].w);
            if (st) os[(i * BATCH + j) * DV] = y;
        }
        // Keep this iteration's ds_reads from sinking past the next issue()
        // (which overwrites slot (i+1)&3 == this slot on the next wrap).
        __builtin_amdgcn_sched_barrier(0);
    };

    issue(0); issue(1); issue(2);

    if (chunk != 0) {
        // Warm-up: batches 0..7 over [t0-W, t0), no stores. Wait keeps 3
        // batches (24 loads) in flight.
        for (int i = 0; i < 8; ++i) { issue(i + 3); WAITVM(24); consume(i, false); }
        // Store-phase ramp: store counts join the vmcnt window one iter late.
        issue(11); WAITVM(24); consume(8, true);
        issue(12); WAITVM(32); consume(9, true);
        issue(13); WAITVM(40); consume(10, true);
        for (int i = 11; i < 40; ++i) { issue(i + 3); WAITVM(48); consume(i, true); }
    } else {
        // chunk 0: no warm-up. y-init = x0 read back from LDS (avoids a plain
        // global load that would perturb vmcnt accounting); first step then
        // computes 0.1*x0 + 0.9*x0 = x0 exactly.
        issue(3); WAITVM(24); y = ring[0][0][lane]; consume(0, true);
        issue(4); WAITVM(32); consume(1, true);
        issue(5); WAITVM(40); consume(2, true);
        for (int i = 3; i < 32; ++i) { issue(i + 3); WAITVM(48); consume(i, true); }
    }
}

extern "C" void kernel_launch(void* const* d_in, const int* in_sizes, int n_in,
                              void* d_out, int out_size, void* d_ws, size_t ws_size,
                              hipStream_t stream) {
    const float4* X = (const float4*)d_in[0];
    float4*       O = (float4*)d_out;

    const int total_threads = B * C * DV;    // 32768
    const int block = 64;
    const int grid  = total_threads / block; // 512 blocks
    ema_lds_pipe<<<grid, block, 0, stream>>>(X, O);
}